// Round 1
// baseline (327.041 us; speedup 1.0000x reference)
//
#include <hip/hip_runtime.h>

// Problem constants (match reference setup_inputs)
#define BB 32
#define TT 1024
#define NN 512
#define CC 3
#define PS 2
#define NBLK (TT / PS)            // 512
#define ROW_FLOATS (NN * CC)      // 1536 floats per (b,t) row
#define ROW_F4 (ROW_FLOATS / 4)   // 384 float4 per row (6144 B, 16B-aligned)

// One block per (b, t) row. Row copy is fully coalesced float4.
// Channel-0 gather: component k of float4 i is flat offset 4i+k, whose
// channel is (4i+k) % 3 == (i+k) % 3. It comes from the permuted source row
// iff that channel is 0.
__global__ __launch_bounds__(256) void patchperm_kernel(
    const float4* __restrict__ x,
    const int* __restrict__ perm,
    float4* __restrict__ out) {
  const int r = blockIdx.x;          // row index in [0, B*T)
  const int b = r >> 10;             // T == 1024
  const int t = r & (TT - 1);
  const int j = t >> 1;              // PS == 2
  const int jp = perm[b * NBLK + j];
  const int tsrc = (jp << 1) | (t & 1);

  const size_t rowbase = (size_t)r * ROW_F4;
  const float4* __restrict__ cur = x + rowbase;
  float4* __restrict__ o = out + rowbase;

  if (tsrc == t) {
    // Identity block (~75% of rows): straight vectorized copy.
    for (int i = threadIdx.x; i < ROW_F4; i += 256) {
      o[i] = cur[i];
    }
  } else {
    const float4* __restrict__ src =
        x + ((size_t)(b * TT + tsrc)) * ROW_F4;
    for (int i = threadIdx.x; i < ROW_F4; i += 256) {
      const float4 a = cur[i];
      const float4 s = src[i];
      const int m = i % 3;
      float4 w;
      w.x = (m == 0) ? s.x : a.x;  // channel (i+0)%3
      w.y = (m == 2) ? s.y : a.y;  // channel (i+1)%3
      w.z = (m == 1) ? s.z : a.z;  // channel (i+2)%3
      w.w = (m == 0) ? s.w : a.w;  // channel (i+3)%3
      o[i] = w;
    }
  }
}

extern "C" void kernel_launch(void* const* d_in, const int* in_sizes, int n_in,
                              void* d_out, int out_size, void* d_ws, size_t ws_size,
                              hipStream_t stream) {
  const float4* x = (const float4*)d_in[0];
  const int* perm = (const int*)d_in[1];
  float4* out = (float4*)d_out;
  patchperm_kernel<<<BB * TT, 256, 0, stream>>>(x, perm, out);
}